// Round 2
// baseline (178.444 us; speedup 1.0000x reference)
//
#include <hip/hip_runtime.h>

typedef _Float16 f16;
typedef _Float16 f16x4 __attribute__((ext_vector_type(4)));
typedef _Float16 f16x8 __attribute__((ext_vector_type(8)));
typedef float    f32x4 __attribute__((ext_vector_type(4)));

#define S2C 2.88539008177792681472f   // 2*log2(e)

// ws layout, f16-element offsets
#define OFF_ST16 0u          // states f16   [8192][10][64]   5242880
#define OFF_AC16 5242880u    // action f16   [8192][10][16]   1310720
#define OFF_WEF  6553600u    // W_edge frags [90][4ks][8cg][64l][8]  1474560
#define OFF_WNF  8028160u    // W_node frags [10][7ks][4c][64l][8]   143360
#define OFF_BE2  8171520u    // f32: be2[11520] then bn2[640]

__device__ __forceinline__ float fast_exp2(float x){
#if __has_builtin(__builtin_amdgcn_exp2f)
    return __builtin_amdgcn_exp2f(x);
#else
    return exp2f(x);
#endif
}
__device__ __forceinline__ float fast_rcp(float x){
#if __has_builtin(__builtin_amdgcn_rcpf)
    return __builtin_amdgcn_rcpf(x);
#else
    return 1.0f/x;
#endif
}

__device__ __forceinline__ void gl_lds16(const f16* g, f16* l){
    __builtin_amdgcn_global_load_lds(
        (const __attribute__((address_space(1))) unsigned int*)g,
        (__attribute__((address_space(3))) unsigned int*)l, 16, 0, 0);
}

#define MFMA16(a,b,c) __builtin_amdgcn_mfma_f32_16x16x32_f16(a,b,c,0,0,0)

// ---------------- fused prologue: cvt + fragment-order + bias scale ----------------
__global__ void prep(const float* __restrict__ st, const float* __restrict__ ac,
                     const float* __restrict__ We, const float* __restrict__ be,
                     const float* __restrict__ Wn, const float* __restrict__ bn,
                     f16* __restrict__ ws16){
    const int bid = blockIdx.x, t = threadIdx.x;
    if (bid < 5120){                                   // states f32 -> f16
        int g = bid*256 + t;
        const float4 v = ((const float4*)st)[g];
        f16x4 h; h[0]=(f16)v.x; h[1]=(f16)v.y; h[2]=(f16)v.z; h[3]=(f16)v.w;
        *(f16x4*)(ws16 + OFF_ST16 + (size_t)g*4) = h;
    } else if (bid < 6400){                            // action f32 -> f16
        int g = (bid-5120)*256 + t;
        const float4 v = ((const float4*)ac)[g];
        f16x4 h; h[0]=(f16)v.x; h[1]=(f16)v.y; h[2]=(f16)v.z; h[3]=(f16)v.w;
        *(f16x4*)(ws16 + OFF_AC16 + (size_t)g*4) = h;
    } else if (bid < 7120){                            // W_edge -> B-fragment order
        int g = (bid-6400)*256 + t;                    // < 184320
        int l = g & 15, q = (g>>4)&3, cg = (g>>6)&7, ks = (g>>9)&3, e = g>>11;
        const float* src = We + e*16384 + (ks*32 + q*8)*128 + cg*16 + l;
        f16x8 h;
        #pragma unroll
        for (int u=0;u<8;u++) h[u] = (f16)src[u*128];
        *(f16x8*)(ws16 + OFF_WEF + (size_t)g*8) = h;
    } else if (bid < 7190){                            // W_node -> B-fragment order (f>=208 zero)
        int g = (bid-7120)*256 + t;                    // < 17920
        int l = g&15, q = (g>>4)&3, c = (g>>6)&3, r = g>>8;
        int ks = r % 7, k = r / 7;
        f16x8 h;
        #pragma unroll
        for (int u=0;u<8;u++){
            int f = ks*32 + q*8 + u;
            h[u] = (f < 208) ? (f16)Wn[k*13312 + f*64 + c*16 + l] : (f16)0.0f;
        }
        *(f16x8*)(ws16 + OFF_WNF + (size_t)k*14336 + ((ks*4 + c)*64 + q*16 + l)*8) = h;
    } else {                                           // biases * 2log2e
        int g = (bid-7190)*256 + t;
        float* be2 = (float*)(ws16 + OFF_BE2);
        if (g < 11520)      be2[g] = S2C*be[g];
        else if (g < 12160) be2[g] = S2C*bn[g-11520];
    }
}

// ---------------- main fused kernel ----------------
__launch_bounds__(256, 3)
__global__ void gnn_main(const f16* __restrict__ ws16, float* __restrict__ out){
    const f16* st  = ws16 + OFF_ST16;
    const f16* ac  = ws16 + OFF_AC16;
    const f16* Wef = ws16 + OFF_WEF;
    const f16* Wnf = ws16 + OFF_WNF;
    const float* be2 = (const float*)(ws16 + OFF_BE2);
    const float* bn2 = be2 + 11520;

    // sAi [128][64] @0 ; sAj0 @8192 ; sAj1 @16384 ; sAct [128][16] @24576
    // stage2: sAgg [128][128] overlays 8192..24575
    __shared__ alignas(16) f16 S[26624];               // 53248 B -> 3 blocks/CU

    const int t = threadIdx.x, lane = t&63, wid = t>>6;
    const int b0 = blockIdx.x*128;
    const int i  = blockIdx.y;
    const int l15 = lane&15, q = lane>>4, qo = q<<3;
    const int wr = (wid>>1)*64, wc = (wid&1)*64;
    const int lr = lane>>3, lc = lane&7;
    const int swz = lc ^ (lr&7);                       // staged chunk swizzle (8-chunk rows)

    // ---- stage sAi, sAct, sAj[buf0] via async global->LDS ----
    {
        const f16* gs = st + (size_t)b0*640 + i*64;
        #pragma unroll
        for (int it=0; it<4; ++it){
            int r0 = (wid*4+it)*8;
            gl_lds16(gs + (size_t)(r0+lr)*640 + swz*8, S + r0*64);
        }
        {   // action: 32 rows per wave-instr, 2 chunks/row, swizzle ^(row&1)
            int r0 = wid*32; int row = r0 + (lane>>1); int ch = (lane&1) ^ (row&1);
            gl_lds16(ac + (size_t)(b0+row)*160 + i*16 + ch*8, S + 24576 + r0*16);
        }
        int j0 = (i==0) ? 1 : 0;
        const f16* gj = st + (size_t)b0*640 + j0*64;
        #pragma unroll
        for (int it=0; it<4; ++it){
            int r0 = (wid*4+it)*8;
            gl_lds16(gj + (size_t)(r0+lr)*640 + swz*8, S + 8192 + r0*64);
        }
    }
    __syncthreads();

    f32x4 agg[4][4] = {};

    #pragma unroll 1
    for (int e=0; e<9; ++e){
        if (e < 8){                                    // prefetch next j into alternate buffer
            int j2 = (e+1) + ((e+1) >= i);
            const f16* gj = st + (size_t)b0*640 + j2*64;
            f16* dst = S + 8192 + (((e+1)&1)<<13);
            #pragma unroll
            for (int it=0; it<4; ++it){
                int r0 = (wid*4+it)*8;
                gl_lds16(gj + (size_t)(r0+lr)*640 + swz*8, dst + r0*64);
            }
        }
        const int bufb  = 8192 + ((e&1)<<13);
        const int ebase = 9*i + e;

        #pragma unroll
        for (int h=0; h<2; ++h){                       // column halves keep VGPR <= 3 waves/SIMD
            f32x4 msg[4][2] = {};
            #pragma unroll
            for (int ks=0; ks<4; ++ks){
                int cg0 = (wid&1)*4 + h*2;
                const f16* wb = Wef + (size_t)((ebase*4 + ks)*8 + cg0)*512 + lane*8;
                f16x8 w0 = *(const f16x8*)wb;
                f16x8 w1 = *(const f16x8*)(wb + 512);
                int ab = (ks<2) ? 0 : bufb;
                int ch = (ks&1)*4 + q;                 // k-chunk within region
                f16x8 af[4];
                #pragma unroll
                for (int rt=0; rt<4; ++rt){
                    int row = wr + rt*16 + l15;
                    af[rt] = *(const f16x8*)(S + ab + row*64 + ((ch ^ (l15&7))<<3));
                }
                #pragma unroll
                for (int rt=0; rt<4; ++rt){
                    msg[rt][0] = MFMA16(af[rt], w0, msg[rt][0]);
                    msg[rt][1] = MFMA16(af[rt], w1, msg[rt][1]);
                }
            }
            // tanh + aggregate:  sum tanh = 9 - 2*sum r  (fold +1 -> +9 at the end)
            #pragma unroll
            for (int c=0; c<2; ++c){
                float bv = be2[ebase*128 + wc + (h*2+c)*16 + l15];
                #pragma unroll
                for (int rt=0; rt<4; ++rt)
                    #pragma unroll
                    for (int r2=0; r2<4; ++r2){
                        float tt = __builtin_fmaf(msg[rt][c][r2], S2C, bv);
                        float rr = fast_rcp(fast_exp2(tt) + 1.0f);
                        agg[rt][h*2+c][r2] = __builtin_fmaf(-2.0f, rr, agg[rt][h*2+c][r2]);
                    }
            }
        }
        __syncthreads();
    }

    // ---- agg (C-layout) -> sAgg f16 (A-layout, swizzled), +9 fold ----
    #pragma unroll
    for (int rt=0; rt<4; ++rt)
        #pragma unroll
        for (int c=0; c<4; ++c)
            #pragma unroll
            for (int r2=0; r2<4; ++r2){
                int row = wr + rt*16 + q*4 + r2;
                int col = wc + c*16 + l15;
                int ch = (col>>3) ^ (row&7);
                S[8192 + row*128 + ch*8 + (col&7)] = (f16)(agg[rt][c][r2] + 9.0f);
            }
    __syncthreads();

    // ---- stage 2: out = tanh([states|action|agg] @ W_node[i] + b_node[i]) ----
    f32x4 acc[2][4] = {};
    const f16* wnb = Wnf + (size_t)i*14336;
    #pragma unroll
    for (int ks=0; ks<7; ++ks){
        int kk = ks*32 + qo;
        f16x8 af[2], bf[4];
        #pragma unroll
        for (int rt=0; rt<2; ++rt){
            int row = wid*32 + rt*16 + l15;
            f16x8 a;
            if (kk < 64)       a = *(const f16x8*)(S + row*64  + (((kk>>3)      ^ (l15&7))<<3));
            else if (kk < 80)  a = *(const f16x8*)(S + 24576 + row*16 + ((((kk-64)>>3) ^ (l15&1))<<3));
            else if (kk < 208) a = *(const f16x8*)(S + 8192  + row*128 + ((((kk-80)>>3) ^ (l15&7))<<3));
            else { f16x8 z; 
                   #pragma unroll
                   for (int u=0;u<8;u++) z[u]=(f16)0.0f; a = z; }
            af[rt] = a;
        }
        #pragma unroll
        for (int c=0; c<4; ++c)
            bf[c] = *(const f16x8*)(wnb + (size_t)((ks*4+c)*64)*8 + lane*8);
        #pragma unroll
        for (int rt=0; rt<2; ++rt)
            #pragma unroll
            for (int c=0; c<4; ++c)
                acc[rt][c] = MFMA16(af[rt], bf[c], acc[rt][c]);
    }
    float bnv[4];
    #pragma unroll
    for (int c=0; c<4; ++c) bnv[c] = bn2[i*64 + c*16 + l15];
    #pragma unroll
    for (int rt=0; rt<2; ++rt)
        #pragma unroll
        for (int c=0; c<4; ++c)
            #pragma unroll
            for (int r2=0; r2<4; ++r2){
                int row = wid*32 + rt*16 + q*4 + r2;
                int col = c*16 + l15;
                float tt = __builtin_fmaf(acc[rt][c][r2], S2C, bnv[c]);
                float rr = fast_rcp(fast_exp2(tt) + 1.0f);
                out[((size_t)(b0+row)*10 + i)*64 + col] = __builtin_fmaf(-2.0f, rr, 1.0f);
            }
}

extern "C" void kernel_launch(void* const* d_in, const int* in_sizes, int n_in,
                              void* d_out, int out_size, void* d_ws, size_t ws_size,
                              hipStream_t stream) {
    const float* states = (const float*)d_in[0];
    const float* action = (const float*)d_in[1];
    const float* W_edge = (const float*)d_in[2];
    const float* b_edge = (const float*)d_in[3];
    const float* W_node = (const float*)d_in[4];
    const float* b_node = (const float*)d_in[5];
    f16* ws16 = (f16*)d_ws;   // ~15.7 MB used

    hipLaunchKernelGGL(prep, dim3(7238), dim3(256), 0, stream,
                       states, action, W_edge, b_edge, W_node, b_node, ws16);
    hipLaunchKernelGGL(gnn_main, dim3(64, 10), dim3(256), 0, stream,
                       ws16, (float*)d_out);
}

// Round 3
// 142.255 us; speedup vs baseline: 1.2544x; 1.2544x over previous
//
#include <hip/hip_runtime.h>

typedef _Float16 f16;
typedef _Float16 f16x4 __attribute__((ext_vector_type(4)));
typedef _Float16 f16x8 __attribute__((ext_vector_type(8)));
typedef float    f32x4 __attribute__((ext_vector_type(4)));

#define S2C 2.88539008177792681472f   // 2*log2(e)

// ws layout, f16-element offsets
#define OFF_ST16 0u          // states f16   [8192][10][64]   5242880
#define OFF_AC16 5242880u    // action f16   [8192][10][16]   1310720
#define OFF_WEF  6553600u    // W_edge frags [90][4ks][8cg][64l][8]  1474560
#define OFF_WNF  8028160u    // W_node frags [10][7ks][4c][64l][8]   143360
#define OFF_BE2  8171520u    // f32: be2[11520] then bn2[640]

__device__ __forceinline__ float fast_exp2(float x){
#if __has_builtin(__builtin_amdgcn_exp2f)
    return __builtin_amdgcn_exp2f(x);
#else
    return exp2f(x);
#endif
}
__device__ __forceinline__ float fast_rcp(float x){
#if __has_builtin(__builtin_amdgcn_rcpf)
    return __builtin_amdgcn_rcpf(x);
#else
    return 1.0f/x;
#endif
}

__device__ __forceinline__ void gl_lds16(const f16* g, f16* l){
    __builtin_amdgcn_global_load_lds(
        (const __attribute__((address_space(1))) unsigned int*)g,
        (__attribute__((address_space(3))) unsigned int*)l, 16, 0, 0);
}

#define MFMA16(a,b,c) __builtin_amdgcn_mfma_f32_16x16x32_f16(a,b,c,0,0,0)

// ---------------- fused prologue: cvt + fragment-order + bias scale ----------------
__global__ void prep(const float* __restrict__ st, const float* __restrict__ ac,
                     const float* __restrict__ We, const float* __restrict__ be,
                     const float* __restrict__ Wn, const float* __restrict__ bn,
                     f16* __restrict__ ws16){
    const int bid = blockIdx.x, t = threadIdx.x;
    if (bid < 5120){                                   // states f32 -> f16
        int g = bid*256 + t;
        const float4 v = ((const float4*)st)[g];
        f16x4 h; h[0]=(f16)v.x; h[1]=(f16)v.y; h[2]=(f16)v.z; h[3]=(f16)v.w;
        *(f16x4*)(ws16 + OFF_ST16 + (size_t)g*4) = h;
    } else if (bid < 6400){                            // action f32 -> f16
        int g = (bid-5120)*256 + t;
        const float4 v = ((const float4*)ac)[g];
        f16x4 h; h[0]=(f16)v.x; h[1]=(f16)v.y; h[2]=(f16)v.z; h[3]=(f16)v.w;
        *(f16x4*)(ws16 + OFF_AC16 + (size_t)g*4) = h;
    } else if (bid < 7120){                            // W_edge -> B-fragment order
        int g = (bid-6400)*256 + t;                    // < 184320
        int l = g & 15, q = (g>>4)&3, cg = (g>>6)&7, ks = (g>>9)&3, e = g>>11;
        const float* src = We + e*16384 + (ks*32 + q*8)*128 + cg*16 + l;
        f16x8 h;
        #pragma unroll
        for (int u=0;u<8;u++) h[u] = (f16)src[u*128];
        *(f16x8*)(ws16 + OFF_WEF + (size_t)g*8) = h;
    } else if (bid < 7190){                            // W_node -> B-fragment order (f>=208 zero)
        int g = (bid-7120)*256 + t;                    // < 17920
        int l = g&15, q = (g>>4)&3, c = (g>>6)&3, r = g>>8;
        int ks = r % 7, k = r / 7;
        f16x8 h;
        #pragma unroll
        for (int u=0;u<8;u++){
            int f = ks*32 + q*8 + u;
            h[u] = (f < 208) ? (f16)Wn[k*13312 + f*64 + c*16 + l] : (f16)0.0f;
        }
        *(f16x8*)(ws16 + OFF_WNF + (size_t)k*14336 + ((ks*4 + c)*64 + q*16 + l)*8) = h;
    } else {                                           // biases * 2log2e
        int g = (bid-7190)*256 + t;
        float* be2 = (float*)(ws16 + OFF_BE2);
        if (g < 11520)      be2[g] = S2C*be[g];
        else if (g < 12160) be2[g] = S2C*bn[g-11520];
    }
}

// ---------------- main fused kernel: BM=64 rows/block, 1280 blocks ----------------
__launch_bounds__(256, 4)
__global__ void gnn_main(const f16* __restrict__ ws16, float* __restrict__ out){
    const f16* st  = ws16 + OFF_ST16;
    const f16* ac  = ws16 + OFF_AC16;
    const f16* Wef = ws16 + OFF_WEF;
    const f16* Wnf = ws16 + OFF_WNF;
    const float* be2 = (const float*)(ws16 + OFF_BE2);
    const float* bn2 = be2 + 11520;

    // f16 offsets: sAi[64][64]@0, sAj0@4096, sAj1@8192, sAct[64][16]@12288
    // stage2: sAgg[64][128] overlays 4096..12287
    __shared__ alignas(16) f16 S[13312];               // 26624 B -> 6 blocks/CU LDS-cap

    const int t = threadIdx.x, lane = t&63, wid = t>>6;
    const int b0 = blockIdx.x*64;
    const int i  = blockIdx.y;
    const int l15 = lane&15, q = lane>>4, qo = q<<3;
    const int wr = (wid>>1)*32, wc = (wid&1)*64;       // stage-1 wave tile 32x64
    const int lr = lane>>3, lc = lane&7;
    const int swz = lc ^ (lr&7);                       // chunk swizzle for 64-f16 rows

    // ---- stage sAi, sAct, sAj[buf0] via async global->LDS ----
    {
        const f16* gs = st + (size_t)b0*640 + i*64;
        #pragma unroll
        for (int it=0; it<2; ++it){
            int r0 = (wid*2+it)*8;
            gl_lds16(gs + (size_t)(r0+lr)*640 + swz*8, S + r0*64);
        }
        if (wid < 2){  // action: [64][16], 1 instr per wave (32 rows x 2 chunks)
            int r0 = wid*32; int row = r0 + (lane>>1); int ch = (lane&1) ^ (row&1);
            gl_lds16(ac + (size_t)(b0+row)*160 + i*16 + ch*8, S + 12288 + r0*16);
        }
        int j0 = (i==0) ? 1 : 0;
        const f16* gj = st + (size_t)b0*640 + j0*64;
        #pragma unroll
        for (int it=0; it<2; ++it){
            int r0 = (wid*2+it)*8;
            gl_lds16(gj + (size_t)(r0+lr)*640 + swz*8, S + 4096 + r0*64);
        }
    }
    __syncthreads();

    f32x4 agg[2][4] = {};

    #pragma unroll 1
    for (int e=0; e<9; ++e){
        if (e < 8){                                    // prefetch next j into alternate buffer
            int j2 = (e+1) + ((e+1) >= i);
            const f16* gj = st + (size_t)b0*640 + j2*64;
            f16* dst = S + 4096 + (((e+1)&1)<<12);
            #pragma unroll
            for (int it=0; it<2; ++it){
                int r0 = (wid*2+it)*8;
                gl_lds16(gj + (size_t)(r0+lr)*640 + swz*8, dst + r0*64);
            }
        }
        const int bufb  = 4096 + ((e&1)<<12);
        const int ebase = 9*i + e;

        float bv[4];
        #pragma unroll
        for (int c=0; c<4; ++c) bv[c] = be2[ebase*128 + wc + c*16 + l15];

        f32x4 msg[2][4] = {};
        #pragma unroll
        for (int ks=0; ks<4; ++ks){
            const f16* wb = Wef + (size_t)((ebase*4 + ks)*8 + (wid&1)*4)*512 + lane*8;
            f16x8 bf[4];
            #pragma unroll
            for (int c=0; c<4; ++c) bf[c] = *(const f16x8*)(wb + c*512);
            int ab = (ks<2) ? 0 : bufb;
            int ch = (ks&1)*4 + q;                     // k-chunk within 64-f16 row
            f16x8 af[2];
            #pragma unroll
            for (int rt=0; rt<2; ++rt){
                int row = wr + rt*16 + l15;
                af[rt] = *(const f16x8*)(S + ab + row*64 + ((ch ^ (l15&7))<<3));
            }
            #pragma unroll
            for (int rt=0; rt<2; ++rt)
                #pragma unroll
                for (int c=0; c<4; ++c)
                    msg[rt][c] = MFMA16(af[rt], bf[c], msg[rt][c]);
        }
        // tanh + aggregate:  sum tanh = 9 - 2*sum rcp(exp+1)  (+9 folded at end)
        #pragma unroll
        for (int rt=0; rt<2; ++rt)
            #pragma unroll
            for (int c=0; c<4; ++c)
                #pragma unroll
                for (int r2=0; r2<4; ++r2){
                    float tt = __builtin_fmaf(msg[rt][c][r2], S2C, bv[c]);
                    float rr = fast_rcp(fast_exp2(tt) + 1.0f);
                    agg[rt][c][r2] = __builtin_fmaf(-2.0f, rr, agg[rt][c][r2]);
                }
        __syncthreads();
    }

    // ---- agg (C-layout) -> sAgg f16 (A-layout, swizzled), +9 fold ----
    #pragma unroll
    for (int rt=0; rt<2; ++rt)
        #pragma unroll
        for (int c=0; c<4; ++c)
            #pragma unroll
            for (int r2=0; r2<4; ++r2){
                int row = wr + rt*16 + q*4 + r2;
                int col = wc + c*16 + l15;
                int ch = (col>>3) ^ (row&7);
                S[4096 + row*128 + ch*8 + (col&7)] = (f16)(agg[rt][c][r2] + 9.0f);
            }
    __syncthreads();

    // ---- stage 2: out = tanh([states|action|agg] @ W_node[i] + b_node[i]) ----
    // wave tile 16x64: rows wid*16..+16, K = 224 (7 steps, last half zero-padded)
    f32x4 acc[4] = {};
    const f16* wnb = Wnf + (size_t)i*14336;
    #pragma unroll
    for (int ks=0; ks<7; ++ks){
        int kk = ks*32 + qo;
        int row = wid*16 + l15;
        f16x8 a;
        if (kk < 64)       a = *(const f16x8*)(S + row*64 + (((kk>>3) ^ (l15&7))<<3));
        else if (kk < 80)  a = *(const f16x8*)(S + 12288 + row*16 + ((((kk-64)>>3) ^ (l15&1))<<3));
        else if (kk < 208) a = *(const f16x8*)(S + 4096 + row*128 + ((((kk-80)>>3) ^ (l15&7))<<3));
        else { f16x8 z;
               #pragma unroll
               for (int u=0;u<8;u++) z[u]=(f16)0.0f; a = z; }
        f16x8 bf[4];
        #pragma unroll
        for (int c=0; c<4; ++c)
            bf[c] = *(const f16x8*)(wnb + (size_t)((ks*4+c)*64)*8 + lane*8);
        #pragma unroll
        for (int c=0; c<4; ++c)
            acc[c] = MFMA16(a, bf[c], acc[c]);
    }
    float bnv[4];
    #pragma unroll
    for (int c=0; c<4; ++c) bnv[c] = bn2[i*64 + c*16 + l15];
    #pragma unroll
    for (int c=0; c<4; ++c)
        #pragma unroll
        for (int r2=0; r2<4; ++r2){
            int row = wid*16 + q*4 + r2;
            int col = c*16 + l15;
            float tt = __builtin_fmaf(acc[c][r2], S2C, bnv[c]);
            float rr = fast_rcp(fast_exp2(tt) + 1.0f);
            out[((size_t)(b0+row)*10 + i)*64 + col] = __builtin_fmaf(-2.0f, rr, 1.0f);
        }
}

extern "C" void kernel_launch(void* const* d_in, const int* in_sizes, int n_in,
                              void* d_out, int out_size, void* d_ws, size_t ws_size,
                              hipStream_t stream) {
    const float* states = (const float*)d_in[0];
    const float* action = (const float*)d_in[1];
    const float* W_edge = (const float*)d_in[2];
    const float* b_edge = (const float*)d_in[3];
    const float* W_node = (const float*)d_in[4];
    const float* b_node = (const float*)d_in[5];
    f16* ws16 = (f16*)d_ws;   // ~16.3 MB used

    hipLaunchKernelGGL(prep, dim3(7238), dim3(256), 0, stream,
                       states, action, W_edge, b_edge, W_node, b_node, ws16);
    hipLaunchKernelGGL(gnn_main, dim3(128, 10), dim3(256), 0, stream,
                       ws16, (float*)d_out);
}